// Round 7
// baseline (201.570 us; speedup 1.0000x reference)
//
#include <hip/hip_runtime.h>

// CovarianceLayer: out = boxmean5x5( (center(x)-boxmean5x5(x)) * (center(y)-boxmean5x5(y)) )
// x,y: [16,1,1024,1024] fp32; out: [16,1,1016,1016] fp32.
//
// r6 post-mortem: flattened straight-line body improved 85->79us (best) but
// VGPR 68 crossed the 64-VGPR tier -> 4 waves/SIMD cap, occupancy 25%
// (~2 resident/SIMD). Ledger r0..r6: per-SIMD wave-step stuck at
// 1580-1920cy in every variant while VALU<=21%, DS~20%, HBM<=37% -- each
// wave's step is a serial in-order latency chain (~1-1.5k cy of waitcnt on
// loads/shfls/ds) and 2 resident waves cannot overlap it. The one untried
// lever is RESIDENT WAVES.
//
// r7: occupancy experiment. r4's rolled body (proved 44 VGPR -> 8 waves/SIMD
// tier; LDS p-ring 20KB/block -> 8 blocks/CU) + fmaf fusion, with RCHUNK
// 16->8: 16x5x127 = 10160 wave-jobs (~10/SIMD oversubscribed, ~8 resident,
// 4x r6). Cost: +32% total wave-steps (16 steps per 8 output rows) --
// swamped if latency/TLP theory is right; decisive regression if a shared
// fixed floor is right.
//
// Structure (from r4): LDS p-ring per wave (5 slots x 64 lanes x float4, no
// __syncthreads, conflict-free ds_b128); x/y vertical running sums subtract
// an old-row global re-load (L2/L3-hit, prefetched 1 step ahead); center row
// via 2-deep delay regs; rolled loop, ring slot via wrap counter.
//
// Valid outputs per 256-col wave strip: 248 cols (lanes 1..62). 5 strips
// cover 1016. Edge lanes' shfl out-of-range returns own value (finite) ->
// garbage only ever flows into masked-off outputs.

#define W 1024
#define H 1024
#define OW 1016
#define OH 1016
#define NBATCH 16
#define NSTRIP 5
#define NCHUNK 127            // 1016 / RCHUNK
#define RCHUNK 8
#define NSTEP (RCHUNK + 8)    // 16 input rows per job
#define STRIP_OUT 248

typedef float floatx4 __attribute__((ext_vector_type(4)));

__device__ __forceinline__ float shfl_up1(float v) { return __shfl_up(v, 1, 64); }
__device__ __forceinline__ float shfl_dn1(float v) { return __shfl_down(v, 1, 64); }

__global__ __launch_bounds__(256) void cov_kernel(
    const float* __restrict__ x, const float* __restrict__ y,
    float* __restrict__ out)
{
    // per-wave p-ring: [wave][slot][lane] float4
    __shared__ float4 pring[4 * 5 * 64];

    const int wid  = (blockIdx.x << 2) + (threadIdx.x >> 6);
    const int lane = threadIdx.x & 63;
    const int wib  = threadIdx.x >> 6;

    // job decode: chunk fastest (adjacent waves share row halo in L2)
    const int chunk = wid % NCHUNK;
    const int rest  = wid / NCHUNK;
    const int strip = rest % NSTRIP;
    const int batch = rest / NSTRIP;

    const int o0   = chunk * RCHUNK;      // first output row of this job
    const int base = strip * STRIP_OUT;   // first input col of this strip

    int col4 = base + (lane << 2);
    if (col4 > W - 4) col4 = W - 4;       // clamp (strip 4 tail lanes; masked below)

    const float* __restrict__ xb = x + (size_t)batch * H * W;
    const float* __restrict__ yb = y + (size_t)batch * H * W;
    float* __restrict__ ob = out + (size_t)batch * OH * OW;

    const int j4 = base + ((lane - 1) << 2);   // first output col this lane stores
    const bool lane_ok = (lane >= 1) && (lane <= 62) && (j4 <= OW - 4);

    constexpr float inv25 = 1.0f / 25.0f;

    const float4 z4 = make_float4(0.f, 0.f, 0.f, 0.f);
    float4 vx = z4, vy = z4, vp = z4;
    float4 cxA = z4, cxB = z4, cyA = z4, cyB = z4;   // rows r-1, r-2 delay regs

    float4* const prw = &pring[wib * 5 * 64 + lane];  // this wave's ring, lane slot
    int u5 = 0;                                       // ring slot counter

    // prefetch row 0 (new rows); old-row prefetch regs start dead
    float4 xn_n, yn_n, xo_n = z4, yo_n = z4;
    {
        int r = o0; if (r > H - 1) r = H - 1;
        const int off = r * W + col4;
        xn_n = *(const float4*)(xb + off);
        yn_n = *(const float4*)(yb + off);
    }

    #pragma unroll 1
    for (int s = 0; s < NSTEP; ++s) {
        const float4 xn = xn_n, yn = yn_n;
        const float4 xo = xo_n, yo = yo_n;

        // issue next iteration's streamed loads NOW (latency hidden under
        // this step's shfl+VALU chain)
        if (s + 1 < NSTEP) {
            int rn = o0 + s + 1; if (rn > H - 1) rn = H - 1;
            const int offn = rn * W + col4;
            xn_n = *(const float4*)(xb + offn);
            yn_n = *(const float4*)(yb + offn);
            if (s + 1 >= 5) {
                int ro = o0 + s - 4; if (ro > H - 1) ro = H - 1;  // R((s+1)-5)
                const int offo = ro * W + col4;
                xo_n = *(const float4*)(xb + offo);
                yo_n = *(const float4*)(yb + offo);
            }
        }

        // vertical running 5-sums: add row R(s), drop row R(s-5)
        if (s >= 5) {
            vx.x += xn.x - xo.x; vx.y += xn.y - xo.y;
            vx.z += xn.z - xo.z; vx.w += xn.w - xo.w;
            vy.x += yn.x - yo.x; vy.y += yn.y - yo.y;
            vy.z += yn.z - yo.z; vy.w += yn.w - yo.w;
        } else {
            vx.x += xn.x; vx.y += xn.y; vx.z += xn.z; vx.w += xn.w;
            vy.x += yn.x; vy.y += yn.y; vy.z += yn.z; vy.w += yn.w;
        }

        // center row R(s-2) from delay regs
        const float4 cx4 = cxB, cy4 = cyB;
        cxB = cxA; cyB = cyA; cxA = xn; cyA = yn;

        if (s >= 4) {
            // horizontal 5-sums at this lane's 4 cols (neighbors via shfl)
            const float vxl0 = shfl_up1(vx.z), vxl1 = shfl_up1(vx.w);
            const float vxr0 = shfl_dn1(vx.x), vxr1 = shfl_dn1(vx.y);
            const float vyl0 = shfl_up1(vy.z), vyl1 = shfl_up1(vy.w);
            const float vyr0 = shfl_dn1(vy.x), vyr1 = shfl_dn1(vy.y);

            const float hx0 = vxl0 + vxl1 + vx.x + vx.y + vx.z;
            const float hx1 = hx0 - vxl0 + vx.w;
            const float hx2 = hx1 - vxl1 + vxr0;
            const float hx3 = hx2 - vx.x + vxr1;
            const float hy0 = vyl0 + vyl1 + vy.x + vy.y + vy.z;
            const float hy1 = hy0 - vyl0 + vy.w;
            const float hy2 = hy1 - vyl1 + vyr0;
            const float hy3 = hy2 - vy.x + vyr1;

            float4 p;
            p.x = __builtin_fmaf(-inv25, hx0, cx4.x) * __builtin_fmaf(-inv25, hy0, cy4.x);
            p.y = __builtin_fmaf(-inv25, hx1, cx4.y) * __builtin_fmaf(-inv25, hy1, cy4.y);
            p.z = __builtin_fmaf(-inv25, hx2, cx4.z) * __builtin_fmaf(-inv25, hy2, cy4.z);
            p.w = __builtin_fmaf(-inv25, hx3, cx4.w) * __builtin_fmaf(-inv25, hy3, cy4.w);

            // vertical running 5-sum of p; 5-deep history lives in LDS
            float4* const pslot = prw + u5 * 64;
            if (s >= 9) {
                const float4 pold = *pslot;      // ds_read_b128 (own wave's row)
                vp.x += p.x - pold.x; vp.y += p.y - pold.y;
                vp.z += p.z - pold.z; vp.w += p.w - pold.w;
            } else {
                vp.x += p.x; vp.y += p.y; vp.z += p.z; vp.w += p.w;
            }
            *pslot = p;                          // ds_write_b128
            if (++u5 == 5) u5 = 0;

            if (s >= 8) {                        // wave-uniform; i < OH always
                const int i = o0 + s - 8;        // output row
                const float vpl0 = shfl_up1(vp.z), vpl1 = shfl_up1(vp.w);
                const float vpr0 = shfl_dn1(vp.x), vpr1 = shfl_dn1(vp.y);
                const float h0 = vpl0 + vpl1 + vp.x + vp.y + vp.z;
                const float h1 = h0 - vpl0 + vp.w;
                const float h2 = h1 - vpl1 + vpr0;
                const float h3 = h2 - vp.x + vpr1;
                if (lane_ok) {
                    floatx4 o4 = { h0 * inv25, h1 * inv25, h2 * inv25, h3 * inv25 };
                    __builtin_nontemporal_store(o4, (floatx4*)(ob + (size_t)i * OW + j4));
                }
            }
        }
    }
}

extern "C" void kernel_launch(void* const* d_in, const int* in_sizes, int n_in,
                              void* d_out, int out_size, void* d_ws, size_t ws_size,
                              hipStream_t stream) {
    const float* x = (const float*)d_in[0];
    const float* y = (const float*)d_in[1];
    // d_in[2]/d_in[3]: constant conv masks (1/25 box, center impulse) — baked in.
    float* out = (float*)d_out;

    // 16 batch x 5 strips x 127 row-chunks = 10160 wave-jobs = 2540 blocks x 4 waves
    dim3 grid(NBATCH * NSTRIP * NCHUNK / 4);
    dim3 block(256);
    hipLaunchKernelGGL(cov_kernel, grid, block, 0, stream, x, y, out);
}

// Round 9
// 191.410 us; speedup vs baseline: 1.0531x; 1.0531x over previous
//
#include <hip/hip_runtime.h>

// CovarianceLayer: out = boxmean5x5( (center(x)-boxmean5x5(x)) * (center(y)-boxmean5x5(y)) )
// x,y: [16,1,1024,1024] fp32; out: [16,1,1016,1016] fp32.
//
// r8 post-mortem: DPP directions were REVERSED (absmax 1.18, column shift).
// AMD DPP semantics (cf. the canonical row_shr:1 prefix-scan): "shift right"
// reads from LOWER lanes -- wave_shr:1 (0x138) = lane d gets lane d-1
// (= __shfl_up); wave_shl:1 (0x130) = lane d gets lane d+1 (= __shfl_down).
// r9 = r8 with the two ctrl codes swapped; nothing else changed.
//
// Rationale (r7 post-mortem): occupancy 25->45% bought only 1.16x step
// throughput; serial in-wave latency chain dominates, biggest item = 12
// __shfl/step (ds_bpermute + lgkmcnt, ~120cy each, ~3 dependent clusters).
// DPP lane shifts are single-cycle VALU ops -- no DS pipe, no lgkmcnt.
// Base = r6 flattened kernel (79us best). Remaining DS ops: only the 2
// p-ring accesses per step.
//
// Valid outputs per 256-col wave strip: 248 cols (lanes 1..62). 5 strips
// cover 1016. Edge lanes keep own value on the wave-boundary shift
// (old=src, bound_ctrl=false) -> garbage only flows into masked-off outputs.

#define W 1024
#define H 1024
#define OW 1016
#define OH 1016
#define NBATCH 16
#define NSTRIP 5
#define NCHUNK 64
#define RCHUNK 16
#define NSTEP (RCHUNK + 8)    // 24 input rows per job
#define STRIP_OUT 248

typedef float floatx4 __attribute__((ext_vector_type(4)));

// lane d gets lane d-1's value (wave_shr:1 = 0x138); lane 0 keeps own
// (bound_ctrl=false, old=src). Matches __shfl_up(v,1,64).
__device__ __forceinline__ float up1(float v) {
    int r = __builtin_amdgcn_update_dpp(__float_as_int(v), __float_as_int(v),
                                        0x138, 0xF, 0xF, false);
    return __int_as_float(r);
}
// lane d gets lane d+1's value (wave_shl:1 = 0x130); lane 63 keeps own.
// Matches __shfl_down(v,1,64).
__device__ __forceinline__ float dn1(float v) {
    int r = __builtin_amdgcn_update_dpp(__float_as_int(v), __float_as_int(v),
                                        0x130, 0xF, 0xF, false);
    return __int_as_float(r);
}

__global__ __launch_bounds__(256) void cov_kernel(
    const float* __restrict__ x, const float* __restrict__ y,
    float* __restrict__ out)
{
    // per-wave p-ring: [wave][slot][lane] float4
    __shared__ float4 pring[4 * 5 * 64];

    const int wid  = (blockIdx.x << 2) + (threadIdx.x >> 6);
    const int lane = threadIdx.x & 63;
    const int wib  = threadIdx.x >> 6;

    // job decode: chunk fastest (adjacent waves share row halo in L2)
    const int chunk = wid & (NCHUNK - 1);
    const int rest  = wid >> 6;
    const int strip = rest % NSTRIP;
    const int batch = rest / NSTRIP;

    const int o0   = chunk * RCHUNK;      // first output row of this job
    const int base = strip * STRIP_OUT;   // first input col of this strip

    int col4 = base + (lane << 2);
    if (col4 > W - 4) col4 = W - 4;       // clamp (strip 4 tail lanes; masked below)

    const float* __restrict__ xb = x + (size_t)batch * H * W;
    const float* __restrict__ yb = y + (size_t)batch * H * W;
    float* __restrict__ ob = out + (size_t)batch * OH * OW;

    const int j4 = base + ((lane - 1) << 2);   // first output col this lane stores
    const bool lane_ok = (lane >= 1) && (lane <= 62) && (j4 <= OW - 4);

    constexpr float inv25 = 1.0f / 25.0f;

    const float4 z4 = make_float4(0.f, 0.f, 0.f, 0.f);
    float4 vx = z4, vy = z4, vp = z4;
    float4 cxA = z4, cxB = z4, cyA = z4, cyB = z4;   // rows r-1, r-2 delay regs

    float4* const prw = &pring[wib * 5 * 64 + lane];  // this wave's ring, lane slot

    // prefetch row 0 (new rows); old-row prefetch regs start dead
    float4 xn_n, yn_n, xo_n = z4, yo_n = z4;
    {
        int r = o0; if (r > H - 1) r = H - 1;
        const int off = r * W + col4;
        xn_n = *(const float4*)(xb + off);
        yn_n = *(const float4*)(yb + off);
    }

// One scan step. SRT: runtime step index. Flags (compile-time constants):
// COLDPF: prefetch old row (for step SRT+1's subtract)   [SRT >= 4]
// CSUB  : vertical sums subtract old row                 [SRT >= 5]
// CP    : compute p, write ring                          [SRT >= 4]
// CRD   : read ring, subtract p(SRT-5) from vp           [SRT >= 9]
// SLOT  : ring slot, (SRT-4) % 5, static
// CEMIT : emit output row o0 + SRT - 8                   [SRT >= 8]
#define STEPX(SRT, COLDPF, CSUB, CP, CRD, SLOT, CEMIT) do {                    \
    const float4 xn = xn_n, yn = yn_n;                                         \
    const float4 xo = xo_n, yo = yo_n;                                         \
    { int rn_ = o0 + (SRT) + 1; if (rn_ > H - 1) rn_ = H - 1;                  \
      const size_t ro4_ = (size_t)rn_ * W + col4;                              \
      xn_n = *(const float4*)(xb + ro4_);                                      \
      yn_n = *(const float4*)(yb + ro4_); }                                    \
    if (COLDPF) {                                                              \
      int ro_ = o0 + (SRT) - 4; if (ro_ > H - 1) ro_ = H - 1;                  \
      const size_t rr4_ = (size_t)ro_ * W + col4;                              \
      xo_n = *(const float4*)(xb + rr4_);                                      \
      yo_n = *(const float4*)(yb + rr4_); }                                    \
    if (CSUB) {                                                                \
      vx.x += xn.x - xo.x; vx.y += xn.y - xo.y;                                \
      vx.z += xn.z - xo.z; vx.w += xn.w - xo.w;                                \
      vy.x += yn.x - yo.x; vy.y += yn.y - yo.y;                                \
      vy.z += yn.z - yo.z; vy.w += yn.w - yo.w;                                \
    } else {                                                                   \
      vx.x += xn.x; vx.y += xn.y; vx.z += xn.z; vx.w += xn.w;                  \
      vy.x += yn.x; vy.y += yn.y; vy.z += yn.z; vy.w += yn.w;                  \
    }                                                                          \
    const float4 cx4 = cxB, cy4 = cyB;                                         \
    cxB = cxA; cyB = cyA; cxA = xn; cyA = yn;                                  \
    if (CP) {                                                                  \
      const float vxl0 = up1(vx.z), vxl1 = up1(vx.w);                          \
      const float vyl0 = up1(vy.z), vyl1 = up1(vy.w);                          \
      const float vxr0 = dn1(vx.x), vxr1 = dn1(vx.y);                          \
      const float vyr0 = dn1(vy.x), vyr1 = dn1(vy.y);                          \
      const float hx0 = vxl0 + vxl1 + vx.x + vx.y + vx.z;                      \
      const float hx1 = hx0 - vxl0 + vx.w;                                     \
      const float hx2 = hx1 - vxl1 + vxr0;                                     \
      const float hx3 = hx2 - vx.x + vxr1;                                     \
      const float hy0 = vyl0 + vyl1 + vy.x + vy.y + vy.z;                      \
      const float hy1 = hy0 - vyl0 + vy.w;                                     \
      const float hy2 = hy1 - vyl1 + vyr0;                                     \
      const float hy3 = hy2 - vy.x + vyr1;                                     \
      float4 p;                                                                \
      p.x = __builtin_fmaf(-inv25, hx0, cx4.x) * __builtin_fmaf(-inv25, hy0, cy4.x); \
      p.y = __builtin_fmaf(-inv25, hx1, cx4.y) * __builtin_fmaf(-inv25, hy1, cy4.y); \
      p.z = __builtin_fmaf(-inv25, hx2, cx4.z) * __builtin_fmaf(-inv25, hy2, cy4.z); \
      p.w = __builtin_fmaf(-inv25, hx3, cx4.w) * __builtin_fmaf(-inv25, hy3, cy4.w); \
      float4* const pslot_ = prw + (SLOT) * 64;                                \
      if (CRD) {                                                               \
        const float4 pold_ = *pslot_;         /* ds_read_b128, own wave row */ \
        vp.x += p.x - pold_.x; vp.y += p.y - pold_.y;                          \
        vp.z += p.z - pold_.z; vp.w += p.w - pold_.w;                          \
      } else {                                                                 \
        vp.x += p.x; vp.y += p.y; vp.z += p.z; vp.w += p.w;                    \
      }                                                                        \
      *pslot_ = p;                            /* ds_write_b128 */              \
      if (CEMIT) {                                                             \
        const int i_ = o0 + (SRT) - 8;                                         \
        const float vpl0 = up1(vp.z), vpl1 = up1(vp.w);                        \
        const float vpr0 = dn1(vp.x), vpr1 = dn1(vp.y);                        \
        const float h0 = vpl0 + vpl1 + vp.x + vp.y + vp.z;                     \
        const float h1 = h0 - vpl0 + vp.w;                                     \
        const float h2 = h1 - vpl1 + vpr0;                                     \
        const float h3 = h2 - vp.x + vpr1;                                     \
        if (lane_ok && i_ < OH) {                                              \
          floatx4 o4_ = { h0 * inv25, h1 * inv25, h2 * inv25, h3 * inv25 };    \
          __builtin_nontemporal_store(o4_, (floatx4*)(ob + (size_t)i_ * OW + j4)); \
        }                                                                      \
      }                                                                        \
    }                                                                          \
} while (0)

    // prologue: steps 0..8 (priming; first output row emitted at s=8)
    STEPX(0, false, false, false, false, 0, false);
    STEPX(1, false, false, false, false, 0, false);
    STEPX(2, false, false, false, false, 0, false);
    STEPX(3, false, false, false, false, 0, false);
    STEPX(4, true,  false, true,  false, 0, false);
    STEPX(5, true,  true,  true,  false, 1, false);
    STEPX(6, true,  true,  true,  false, 2, false);
    STEPX(7, true,  true,  true,  false, 3, false);
    STEPX(8, true,  true,  true,  false, 4, true);

    // steady state: steps 9..23, branch-free, static ring slots
    #pragma unroll
    for (int k = 0; k < 3; ++k) {
        const int sb = 9 + 5 * k;
        STEPX(sb + 0, true, true, true, true, 0, true);
        STEPX(sb + 1, true, true, true, true, 1, true);
        STEPX(sb + 2, true, true, true, true, 2, true);
        STEPX(sb + 3, true, true, true, true, 3, true);
        STEPX(sb + 4, true, true, true, true, 4, true);
    }
#undef STEPX
}

extern "C" void kernel_launch(void* const* d_in, const int* in_sizes, int n_in,
                              void* d_out, int out_size, void* d_ws, size_t ws_size,
                              hipStream_t stream) {
    const float* x = (const float*)d_in[0];
    const float* y = (const float*)d_in[1];
    // d_in[2]/d_in[3]: constant conv masks (1/25 box, center impulse) — baked in.
    float* out = (float*)d_out;

    // 16 batch x 5 strips x 64 row-chunks = 5120 wave-jobs = 1280 blocks x 4 waves
    dim3 grid(NBATCH * NSTRIP * NCHUNK / 4);
    dim3 block(256);
    hipLaunchKernelGGL(cov_kernel, grid, block, 0, stream, x, y, out);
}